// Round 15
// baseline (366.111 us; speedup 1.0000x reference)
//
#include <hip/hip_runtime.h>
#include <hip/hip_bf16.h>

#define BB 32
#define SS 2048
#define DD 1024
#define UU 1024
#define MBLK 128
#define AST 80  // A LDS row stride in shorts (160 B)

typedef short bf16x8 __attribute__((ext_vector_type(8)));
typedef float f32x4 __attribute__((ext_vector_type(4)));
typedef unsigned int u32;

__device__ __forceinline__ unsigned short f2bf(float x) {
    union { float f; unsigned int u; } v; v.f = x;
    unsigned int r = v.u + 0x7fffu + ((v.u >> 16) & 1u);
    return (unsigned short)(r >> 16);
}

__device__ __forceinline__ f32x4 ntload4(const float* p) {
    return __builtin_nontemporal_load(reinterpret_cast<const f32x4*>(p));
}

__device__ __forceinline__ u32 cvtpk(float lo, float hi) {
    u32 r;
    asm("v_cvt_pk_bf16_f32 %0, %1, %2" : "=v"(r) : "v"(lo), "v"(hi));
    return r;
}

// ---------------- K0: zero score + ctx accumulators ----------------
__global__ void zero_kernel(float* __restrict__ score, float* __restrict__ ctx) {
    const int i = blockIdx.x * 256 + threadIdx.x;
    if (i < BB * SS) score[i] = 0.f;
    else ctx[i - BB * SS] = 0.f;
}

// ---------------- K1a: q_proj = query@w1 + b1 + b2 ----------------
__global__ void qproj_kernel(const float* __restrict__ query, const float* __restrict__ w1,
                             const float* __restrict__ b1, const float* __restrict__ b2,
                             float* __restrict__ qp2) {
    __shared__ float qs[DD];
    const int b = blockIdx.x;   // 32
    const int uc = blockIdx.y;  // 4
    const int t = threadIdx.x;  // 256
    for (int i = t; i < DD; i += 256) qs[i] = query[b * DD + i];
    __syncthreads();
    const int u = uc * 256 + t;
    float acc = 0.f;
#pragma unroll 4
    for (int d = 0; d < DD; ++d) acc = fmaf(qs[d], w1[d * UU + u], acc);
    qp2[b * UU + u] = acc + b1[u] + b2[u];
}

// ---------------- K1b: fragment-packed B for 16x16x32 (coalesced via LDS) -----
__global__ void w2q_kernel(const float* __restrict__ w2, unsigned short* __restrict__ w2q) {
    __shared__ float tile[64][65];
    const int k0 = (blockIdx.x >> 4) * 64;
    const int u0 = (blockIdx.x & 15) * 64;
    const int t = threadIdx.x;  // 256
    {
        const int kr = t >> 2, uc = (t & 3) * 16;
        const float* src = w2 + (size_t)(k0 + kr) * UU + u0 + uc;
#pragma unroll
        for (int j = 0; j < 4; ++j) {
            f32x4 v = *reinterpret_cast<const f32x4*>(src + j * 4);
            tile[kr][uc + j * 4 + 0] = v[0]; tile[kr][uc + j * 4 + 1] = v[1];
            tile[kr][uc + j * 4 + 2] = v[2]; tile[kr][uc + j * 4 + 3] = v[3];
        }
    }
    __syncthreads();
    const int c = t >> 5;
    const int uqL = c >> 1, ksL = c & 1;
    const int uq = (u0 >> 4) + uqL, ks = (k0 >> 5) + ksL;
#pragma unroll
    for (int li = 0; li < 2; ++li) {
        const int l = (t & 31) * 2 + li;
        const int colL = uqL * 16 + (l & 15);
        const int kL = ksL * 32 + (l >> 4) * 8;
        bf16x8 pk;
#pragma unroll
        for (int e = 0; e < 8; ++e) pk[e] = (short)f2bf(tile[kL + e][colL]);
        *reinterpret_cast<bf16x8*>(&w2q[(size_t)(((uq * 32 + ks) * 64 + l)) * 8]) = pk;
    }
}

// ---------------- K2: fused GEMM + tanh + wv-reduce -> atomic score partials ----
// R14 geometry (1024 blocks (b,stile,uh), 512 thr / 8 waves, wave = 128x64, mf=8,
// acc[8][4] f32x4, BK=64, reg-staged A -> LDS [2][128][80] XOR-swz, packed B frags)
// restructured into 4 PHASES per K-step (16 MFMA each):
//   {8 ds_read aF | B-ring issue -> s_barrier -> lgkmcnt(0) -> sched_barrier(0)
//    -> setprio(1) -> 16 MFMA -> setprio(0)}
// A loads at step-top, stage-write after ph3, swap barrier last. Loads stay in
// flight across barriers (raw s_barrier, compiler-counted vmcnt on reg deps).
__global__ __launch_bounds__(512, 2)
void score_kernel(const float* __restrict__ values, const unsigned short* __restrict__ w2q,
                  const float* __restrict__ qp2, const float* __restrict__ wv,
                  float* __restrict__ score) {
    __shared__ __align__(16) unsigned short Asw[2][MBLK * AST];  // 2 x 20 KB
    __shared__ float ssum[8][MBLK];                               // 4 KB

    const int blk = blockIdx.x;        // 1024
    const int b = blk >> 5;
    const int stile = (blk >> 1) & 15;
    const int uh = blk & 1;
    const int s0 = stile * MBLK;
    const int tid = threadIdx.x;
    const int lane = tid & 63;
    const int wid = tid >> 6;          // 0..7
    const int arow = lane & 15;
    const int h = lane >> 4;           // 0..3
    const int uq0 = uh * 32 + wid * 4;

    // staging: thread (srow 0..127, g 0..3) covers granules g and g+4
    const int srow = tid >> 2;
    const int g = tid & 3;
    const float* pA = values + ((size_t)b * SS + s0 + srow) * DD + g * 8;
    const int wpos0 = srow * AST + (g ^ (srow & 7)) * 8;
    const int wpos1 = srow * AST + ((g + 4) ^ (srow & 7)) * 8;

    const unsigned short* wq = w2q + (size_t)lane * 8;
#define BLOAD(nf, ks) (*reinterpret_cast<const bf16x8*>(wq + ((size_t)(((uq0 + (nf)) * 32 + (ks))) << 9)))

#define READA(aF, mh, ksoff)                                                    \
    {                                                                           \
        _Pragma("unroll")                                                       \
        for (int mf = 0; mf < 4; ++mf) {                                        \
            const int row = (mh) * 64 + mf * 16 + arow;                         \
            const int pos = ((ksoff) + h) ^ (row & 7);                          \
            aF[mf] = *reinterpret_cast<const bf16x8*>(&Ab[row * AST + pos * 8]);\
        }                                                                       \
    }

#define PHASE_SYNC()                                          \
    __builtin_amdgcn_s_barrier();                             \
    asm volatile("s_waitcnt lgkmcnt(0)" ::: "memory");        \
    __builtin_amdgcn_sched_barrier(0);

#define MFMA16(aF, bX, mh)                                                      \
    __builtin_amdgcn_s_setprio(1);                                              \
    _Pragma("unroll")                                                           \
    for (int mf = 0; mf < 4; ++mf)                                              \
        _Pragma("unroll")                                                       \
        for (int nf = 0; nf < 4; ++nf)                                          \
            acc[(mh) * 4 + mf][nf] = __builtin_amdgcn_mfma_f32_16x16x32_bf16(   \
                aF[mf], bX[nf], acc[(mh) * 4 + mf][nf], 0, 0, 0);               \
    __builtin_amdgcn_s_setprio(0);

    f32x4 acc[8][4];
#pragma unroll
    for (int mf = 0; mf < 8; ++mf)
#pragma unroll
        for (int nf = 0; nf < 4; ++nf) { f32x4 z = {0.f, 0.f, 0.f, 0.f}; acc[mf][nf] = z; }

    bf16x8 bC[4], bN[4];
    f32x4 aL0, aL1, aL2, aL3;

    // prologue: stage tile 0, preload bC = B(t=0, ks=0)
    aL0 = ntload4(pA);      aL1 = ntload4(pA + 4);
    aL2 = ntload4(pA + 32); aL3 = ntload4(pA + 36);
    {
        u32* d0 = reinterpret_cast<u32*>(&Asw[0][wpos0]);
        d0[0] = cvtpk(aL0[0], aL0[1]); d0[1] = cvtpk(aL0[2], aL0[3]);
        d0[2] = cvtpk(aL1[0], aL1[1]); d0[3] = cvtpk(aL1[2], aL1[3]);
        u32* d1 = reinterpret_cast<u32*>(&Asw[0][wpos1]);
        d1[0] = cvtpk(aL2[0], aL2[1]); d1[1] = cvtpk(aL2[2], aL2[3]);
        d1[2] = cvtpk(aL3[0], aL3[1]); d1[3] = cvtpk(aL3[2], aL3[3]);
    }
#pragma unroll
    for (int nf = 0; nf < 4; ++nf) bC[nf] = BLOAD(nf, 0);
    asm volatile("s_waitcnt lgkmcnt(0)" ::: "memory");
    __builtin_amdgcn_s_barrier();

#pragma unroll 1
    for (int t = 0; t < 16; ++t) {
        const int cur = t & 1;
        const unsigned short* Ab = Asw[cur];

        // step-top: issue next A tile (deepest cover: 4 phases + stage)
        if (t < 15) {
            const float* pn = pA + (t + 1) * 64;
            aL0 = ntload4(pn);      aL1 = ntload4(pn + 4);
            aL2 = ntload4(pn + 32); aL3 = ntload4(pn + 36);
        }

        // ---- ph0: (ks0, mh0) + issue bN = B(t, ks1) ----
        {
            bf16x8 aF[4];
            READA(aF, 0, 0);
#pragma unroll
            for (int nf = 0; nf < 4; ++nf) bN[nf] = BLOAD(nf, 2 * t + 1);
            PHASE_SYNC();
            MFMA16(aF, bC, 0);
        }
        // ---- ph1: (ks0, mh1) ----
        {
            bf16x8 aF[4];
            READA(aF, 1, 0);
            PHASE_SYNC();
            MFMA16(aF, bC, 1);
        }
        // ---- ph2: (ks1, mh0) + issue bC = B(t+1, ks0) ----
        {
            bf16x8 aF[4];
            READA(aF, 0, 4);
            if (t < 15) {
#pragma unroll
                for (int nf = 0; nf < 4; ++nf) bC[nf] = BLOAD(nf, 2 * t + 2);
            }
            PHASE_SYNC();
            MFMA16(aF, bN, 0);
        }
        // ---- ph3: (ks1, mh1) ----
        {
            bf16x8 aF[4];
            READA(aF, 1, 4);
            PHASE_SYNC();
            MFMA16(aF, bN, 1);
        }

        // ---- stage-write tile t+1 into other buffer ----
        if (t < 15) {
            u32* d0 = reinterpret_cast<u32*>(&Asw[cur ^ 1][wpos0]);
            d0[0] = cvtpk(aL0[0], aL0[1]); d0[1] = cvtpk(aL0[2], aL0[3]);
            d0[2] = cvtpk(aL1[0], aL1[1]); d0[3] = cvtpk(aL1[2], aL1[3]);
            u32* d1 = reinterpret_cast<u32*>(&Asw[cur ^ 1][wpos1]);
            d1[0] = cvtpk(aL2[0], aL2[1]); d1[1] = cvtpk(aL2[2], aL2[3]);
            d1[2] = cvtpk(aL3[0], aL3[1]); d1[3] = cvtpk(aL3[2], aL3[3]);
        }
        asm volatile("s_waitcnt lgkmcnt(0)" ::: "memory");
        __builtin_amdgcn_s_barrier();
    }
#undef BLOAD
#undef READA
#undef PHASE_SYNC
#undef MFMA16

    // epilogue: tanh + wv weighting (16x16 C/D: col=lane&15, row=(lane>>4)*4+i)
    float rowsum[32];
#pragma unroll
    for (int i = 0; i < 32; ++i) rowsum[i] = 0.f;
#pragma unroll
    for (int nf = 0; nf < 4; ++nf) {
        const int u = (uq0 + nf) * 16 + arow;
        const float qv = qp2[b * UU + u];
        const float wvv = wv[u];
#pragma unroll
        for (int mf = 0; mf < 8; ++mf)
#pragma unroll
            for (int i = 0; i < 4; ++i) {
                float hh = acc[mf][nf][i] + qv;
                float e = __expf(2.f * hh);
                float th = 1.f - 2.f / (e + 1.f);
                rowsum[mf * 4 + i] = fmaf(th, wvv, rowsum[mf * 4 + i]);
            }
    }
#pragma unroll
    for (int i = 0; i < 32; ++i) {
        float v = rowsum[i];
        v += __shfl_xor(v, 1);
        v += __shfl_xor(v, 2);
        v += __shfl_xor(v, 4);
        v += __shfl_xor(v, 8);
        rowsum[i] = v;
    }
    if ((lane & 15) == 0) {
        const int rg = lane >> 4;
#pragma unroll
        for (int mf = 0; mf < 8; ++mf)
#pragma unroll
            for (int i = 0; i < 4; ++i)
                ssum[wid][mf * 16 + rg * 4 + i] = rowsum[mf * 4 + i];
    }
    __syncthreads();
    if (tid < MBLK) {
        float sc2 = 0.f;
#pragma unroll
        for (int w = 0; w < 8; ++w) sc2 += ssum[w][tid];
        atomicAdd(&score[b * SS + s0 + tid], sc2);
    }
}

// ---------------- K3a: softmax over S per batch ----------------
__global__ void softmax_kernel(const float* __restrict__ score, float* __restrict__ weights) {
    __shared__ float red[8];
    const int b = blockIdx.x;
    const int t = threadIdx.x;  // 256
    float local[8];
    float mx = -1e30f;
#pragma unroll
    for (int i = 0; i < 8; ++i) {
        local[i] = score[b * SS + i * 256 + t];
        mx = fmaxf(mx, local[i]);
    }
    for (int off = 1; off < 64; off <<= 1) mx = fmaxf(mx, __shfl_xor(mx, off));
    if ((t & 63) == 0) red[t >> 6] = mx;
    __syncthreads();
    const float m = fmaxf(fmaxf(red[0], red[1]), fmaxf(red[2], red[3]));
    float sum = 0.f;
#pragma unroll
    for (int i = 0; i < 8; ++i) {
        local[i] = __expf(local[i] - m);
        sum += local[i];
    }
    for (int off = 1; off < 64; off <<= 1) sum += __shfl_xor(sum, off);
    if ((t & 63) == 0) red[4 + (t >> 6)] = sum;
    __syncthreads();
    const float inv = 1.f / (red[4] + red[5] + red[6] + red[7]);
#pragma unroll
    for (int i = 0; i < 8; ++i) weights[b * SS + i * 256 + t] = local[i] * inv;
}

// ---------------- K3b: context partials, split-S x4, atomicAdd into zeroed ctx ----
__global__ void context_kernel(const float* __restrict__ values, const float* __restrict__ weights,
                               float* __restrict__ ctx) {
    __shared__ float ws[SS / 4];      // 2 KB
    __shared__ f32x4 red[16][16];     // 4 KB
    const int b = blockIdx.x;   // 32
    const int dc = blockIdx.y;  // 16
    const int sh = blockIdx.z;  // 4 s-quarters
    const int t = threadIdx.x;  // 256
    const int sbase = sh * (SS / 4);
    for (int i = t; i < SS / 4; i += 256) ws[i] = weights[b * SS + sbase + i];
    __syncthreads();
    const int dt = t & 15;
    const int ph = t >> 4;
    const int d = dc * 64 + dt * 4;
    const float* vb = values + ((size_t)b * SS + sbase) * DD + d;
    f32x4 acc = {0.f, 0.f, 0.f, 0.f};
#pragma unroll 8
    for (int s = ph; s < SS / 4; s += 16) {
        const float w = ws[s];
        f32x4 v = ntload4(vb + (size_t)s * DD);
        acc[0] = fmaf(w, v[0], acc[0]);
        acc[1] = fmaf(w, v[1], acc[1]);
        acc[2] = fmaf(w, v[2], acc[2]);
        acc[3] = fmaf(w, v[3], acc[3]);
    }
    red[ph][dt] = acc;
    __syncthreads();
    if (t < 16) {
        f32x4 r = red[0][t];
#pragma unroll
        for (int w = 1; w < 16; ++w) {
            f32x4 x = red[w][t];
#pragma unroll
            for (int i = 0; i < 4; ++i) r[i] += x[i];
        }
        float* dst = ctx + (size_t)b * DD + dc * 64 + t * 4;
        atomicAdd(dst + 0, r[0]);
        atomicAdd(dst + 1, r[1]);
        atomicAdd(dst + 2, r[2]);
        atomicAdd(dst + 3, r[3]);
    }
}

extern "C" void kernel_launch(void* const* d_in, const int* in_sizes, int n_in,
                              void* d_out, int out_size, void* d_ws, size_t ws_size,
                              hipStream_t stream) {
    const float* query  = (const float*)d_in[0];
    const float* values = (const float*)d_in[1];
    const float* w1     = (const float*)d_in[2];
    const float* b1     = (const float*)d_in[3];
    const float* w2     = (const float*)d_in[4];
    const float* b2     = (const float*)d_in[5];
    const float* wv     = (const float*)d_in[6];

    float* ctx     = (float*)d_out;                    // [B, D]
    float* weights = (float*)d_out + (size_t)BB * DD;  // [B, S, 1]

    float* qp2           = (float*)d_ws;                                  // 128 KB
    unsigned short* w2q  = (unsigned short*)((char*)d_ws + 131072);       // 2 MB
    float* score         = (float*)((char*)d_ws + 131072 + 2097152);      // 256 KB

    zero_kernel<<<dim3((BB * SS + BB * DD) / 256), 256, 0, stream>>>(score, ctx);
    qproj_kernel<<<dim3(BB, UU / 256), 256, 0, stream>>>(query, w1, b1, b2, qp2);
    w2q_kernel<<<dim3(256), 256, 0, stream>>>(w2, w2q);
    score_kernel<<<dim3(BB * SS / MBLK * 2), 512, 0, stream>>>(values, w2q, qp2, wv, score);
    softmax_kernel<<<dim3(BB), 256, 0, stream>>>(score, weights);
    context_kernel<<<dim3(BB, 16, 4), 256, 0, stream>>>(values, weights, ctx);
}

// Round 16
// 247.932 us; speedup vs baseline: 1.4767x; 1.4767x over previous
//
#include <hip/hip_runtime.h>
#include <hip/hip_bf16.h>

#define BB 32
#define SS 2048
#define DD 1024
#define UU 1024
#define MBLK 64

typedef short bf16x8 __attribute__((ext_vector_type(8)));
typedef float f32x4 __attribute__((ext_vector_type(4)));
typedef int i32x4 __attribute__((ext_vector_type(4)));
typedef unsigned int u32;

__device__ __forceinline__ unsigned short f2bf(float x) {
    union { float f; unsigned int u; } v; v.f = x;
    unsigned int r = v.u + 0x7fffu + ((v.u >> 16) & 1u);
    return (unsigned short)(r >> 16);
}

__device__ __forceinline__ f32x4 ntload4(const float* p) {
    return __builtin_nontemporal_load(reinterpret_cast<const f32x4*>(p));
}

__device__ __forceinline__ u32 cvtpk(float lo, float hi) {
    u32 r;
    asm("v_cvt_pk_bf16_f32 %0, %1, %2" : "=v"(r) : "v"(lo), "v"(hi));
    return r;
}

// ---------------- K0: zero qp2 (qproj accumulates atomically) ----------------
__global__ void zero_kernel(float* __restrict__ qp2) {
    qp2[blockIdx.x * 256 + threadIdx.x] = 0.f;
}

// ---------------- K1a: q_proj partials = query@w1 (+b1+b2 on ds==0) ----------
// grid (4 uc, 8 bgroup, 8 dslice): b-grouping x4 cuts w1 HBM traffic 128->32 MB.
__global__ void qproj_kernel(const float* __restrict__ query, const float* __restrict__ w1,
                             const float* __restrict__ b1, const float* __restrict__ b2,
                             float* __restrict__ qp2) {
    __shared__ float qs[4][128];
    const int uc = blockIdx.x;   // 4
    const int bg = blockIdx.y;   // 8
    const int ds = blockIdx.z;   // 8
    const int t = threadIdx.x;   // 256
    if (t < 128) {
#pragma unroll
        for (int bi = 0; bi < 4; ++bi)
            qs[bi][t] = query[(bg * 4 + bi) * DD + ds * 128 + t];
    }
    __syncthreads();
    const int u = uc * 256 + t;
    float a0 = 0.f, a1 = 0.f, a2 = 0.f, a3 = 0.f;
    const float* wp = w1 + (size_t)(ds * 128) * UU + u;
#pragma unroll 4
    for (int d = 0; d < 128; ++d) {
        const float w = wp[(size_t)d * UU];
        a0 = fmaf(qs[0][d], w, a0);
        a1 = fmaf(qs[1][d], w, a1);
        a2 = fmaf(qs[2][d], w, a2);
        a3 = fmaf(qs[3][d], w, a3);
    }
    const float bb = (ds == 0) ? (b1[u] + b2[u]) : 0.f;
    atomicAdd(&qp2[(bg * 4 + 0) * UU + u], a0 + bb);
    atomicAdd(&qp2[(bg * 4 + 1) * UU + u], a1 + bb);
    atomicAdd(&qp2[(bg * 4 + 2) * UU + u], a2 + bb);
    atomicAdd(&qp2[(bg * 4 + 3) * UU + u], a3 + bb);
}

// ---------------- K1b: fragment-packed B for 16x16x32 (coalesced via LDS) -----
// w2q[((uq*32+ks)*64+lane)*8+e] = bf16(w2[ks*32+(lane>>4)*8+e][uq*16+(lane&15)])
__global__ void w2q_kernel(const float* __restrict__ w2, unsigned short* __restrict__ w2q) {
    __shared__ float tile[64][65];
    const int k0 = (blockIdx.x >> 4) * 64;
    const int u0 = (blockIdx.x & 15) * 64;
    const int t = threadIdx.x;  // 256
    {
        const int kr = t >> 2, uc = (t & 3) * 16;
        const float* src = w2 + (size_t)(k0 + kr) * UU + u0 + uc;
#pragma unroll
        for (int j = 0; j < 4; ++j) {
            f32x4 v = *reinterpret_cast<const f32x4*>(src + j * 4);
            tile[kr][uc + j * 4 + 0] = v[0]; tile[kr][uc + j * 4 + 1] = v[1];
            tile[kr][uc + j * 4 + 2] = v[2]; tile[kr][uc + j * 4 + 3] = v[3];
        }
    }
    __syncthreads();
    const int c = t >> 5;
    const int uqL = c >> 1, ksL = c & 1;
    const int uq = (u0 >> 4) + uqL, ks = (k0 >> 5) + ksL;
#pragma unroll
    for (int li = 0; li < 2; ++li) {
        const int l = (t & 31) * 2 + li;
        const int colL = uqL * 16 + (l & 15);
        const int kL = ksL * 32 + (l >> 4) * 8;
        bf16x8 pk;
#pragma unroll
        for (int e = 0; e < 8; ++e) pk[e] = (short)f2bf(tile[kL + e][colL]);
        *reinterpret_cast<bf16x8*>(&w2q[(size_t)(((uq * 32 + ks) * 64 + l)) * 8]) = pk;
    }
}

// ---------------- K2: fused GEMM + tanh + wv-reduce -> score[b,s] ----------------
// 1024 blocks (b, stile). 512 thr / 8 waves, 1 block/CU (LDS 130 KB).
// Full 64x1024 A-tile staged ONCE into LDS in PACKED-FRAGMENT layout
// (A[mf][ks][lane^((lane>>4)&3)][8]) -> per-lane contiguous 16B ds_reads.
// Then a ZERO-BARRIER U-sweep: per ks, 4 A-frag ds_reads + 8 packed-B 1KB L2
// loads + 32 MFMA (both U-halves interleaved; acc0+acc1 = 128 AGPR). Waves
// decohere -> MFMA/VALU/memory overlap across waves (m114 mechanism).
__global__ __launch_bounds__(512, 2)
void score_kernel(const float* __restrict__ values, const unsigned short* __restrict__ w2q,
                  const float* __restrict__ qp2, const float* __restrict__ wv,
                  const float* __restrict__ bv, float* __restrict__ score) {
    __shared__ __align__(16) unsigned short Apk[MBLK * DD];  // 128 KB packed-frag
    __shared__ float ssum[8][MBLK];                           // 2 KB

    const int blk = blockIdx.x;        // 1024
    const int b = blk >> 5;
    const int s0 = (blk & 31) * MBLK;
    const int tid = threadIdx.x;
    const int lane = tid & 63;
    const int wid = tid >> 6;          // 0..7
    const int arow = lane & 15;

    // ---- stage full A tile: thread (row=tid>>3, g=tid&7), j=0..15 k-granules ----
    // dest: frag(mfb=row>>4, ks=j*2+(g>>2)), lane l=(row&15)+16*(g&3), swz l^=(g&3)
    {
        const int row = tid >> 3;
        const int g = tid & 7;
        const int q = g & 3;
        const int lsw = ((row & 15) + 16 * q) ^ q;
        const float* src = values + ((size_t)b * SS + s0 + row) * DD + g * 8;
        unsigned short* dst = Apk + (size_t)(row >> 4) * 16384 + (size_t)(g >> 2) * 512 + lsw * 8;
#pragma unroll 4
        for (int j = 0; j < 16; ++j) {
            f32x4 x = ntload4(src + j * 64);
            f32x4 y = ntload4(src + j * 64 + 4);
            u32 q0 = cvtpk(x[0], x[1]), q1 = cvtpk(x[2], x[3]);
            u32 q2 = cvtpk(y[0], y[1]), q3 = cvtpk(y[2], y[3]);
            i32x4 w_ = {(int)q0, (int)q1, (int)q2, (int)q3};
            *reinterpret_cast<i32x4*>(dst + (size_t)j * 1024) = w_;
        }
    }
    __syncthreads();
    // ---- zero-barrier compute region from here on ----

    const unsigned short* Ab = Apk + (size_t)(lane ^ ((lane >> 4) & 3)) * 8;
    const unsigned short* wqb = w2q + (size_t)lane * 8;

    f32x4 acc0[4][4], acc1[4][4];
#pragma unroll
    for (int mf = 0; mf < 4; ++mf)
#pragma unroll
        for (int nf = 0; nf < 4; ++nf) {
            f32x4 z = {0.f, 0.f, 0.f, 0.f};
            acc0[mf][nf] = z; acc1[mf][nf] = z;
        }

#pragma unroll 2
    for (int ks = 0; ks < 32; ++ks) {
        bf16x8 aF[4];
#pragma unroll
        for (int mf = 0; mf < 4; ++mf)
            aF[mf] = *reinterpret_cast<const bf16x8*>(Ab + (size_t)(mf * 32 + ks) * 512);
        bf16x8 b0[4], b1[4];
#pragma unroll
        for (int nf = 0; nf < 4; ++nf) {
            b0[nf] = *reinterpret_cast<const bf16x8*>(wqb + (size_t)((wid * 4 + nf) * 32 + ks) * 512);
            b1[nf] = *reinterpret_cast<const bf16x8*>(wqb + (size_t)((32 + wid * 4 + nf) * 32 + ks) * 512);
        }
#pragma unroll
        for (int mf = 0; mf < 4; ++mf)
#pragma unroll
            for (int nf = 0; nf < 4; ++nf)
                acc0[mf][nf] = __builtin_amdgcn_mfma_f32_16x16x32_bf16(
                    aF[mf], b0[nf], acc0[mf][nf], 0, 0, 0);
#pragma unroll
        for (int mf = 0; mf < 4; ++mf)
#pragma unroll
            for (int nf = 0; nf < 4; ++nf)
                acc1[mf][nf] = __builtin_amdgcn_mfma_f32_16x16x32_bf16(
                    aF[mf], b1[nf], acc1[mf][nf], 0, 0, 0);
    }

    // epilogue: tanh + wv weighting (16x16 C/D: col=lane&15 (=u), row=(lane>>4)*4+i (=s))
    float rowsum[16];
#pragma unroll
    for (int i = 0; i < 16; ++i) rowsum[i] = 0.f;
#pragma unroll
    for (int nf = 0; nf < 4; ++nf) {
        const int u0a = (wid * 4 + nf) * 16 + arow;
        const int u1a = (32 + wid * 4 + nf) * 16 + arow;
        const float qv0 = qp2[b * UU + u0a], wv0 = wv[u0a];
        const float qv1 = qp2[b * UU + u1a], wv1 = wv[u1a];
#pragma unroll
        for (int mf = 0; mf < 4; ++mf)
#pragma unroll
            for (int i = 0; i < 4; ++i) {
                float h0 = acc0[mf][nf][i] + qv0;
                float e0 = __expf(2.f * h0);
                rowsum[mf * 4 + i] = fmaf(1.f - 2.f / (e0 + 1.f), wv0, rowsum[mf * 4 + i]);
                float h1 = acc1[mf][nf][i] + qv1;
                float e1 = __expf(2.f * h1);
                rowsum[mf * 4 + i] = fmaf(1.f - 2.f / (e1 + 1.f), wv1, rowsum[mf * 4 + i]);
            }
    }
#pragma unroll
    for (int i = 0; i < 16; ++i) {
        float v = rowsum[i];
        v += __shfl_xor(v, 1);
        v += __shfl_xor(v, 2);
        v += __shfl_xor(v, 4);
        v += __shfl_xor(v, 8);
        rowsum[i] = v;
    }
    if ((lane & 15) == 0) {
        const int rg = lane >> 4;
#pragma unroll
        for (int mf = 0; mf < 4; ++mf)
#pragma unroll
            for (int i = 0; i < 4; ++i)
                ssum[wid][mf * 16 + rg * 4 + i] = rowsum[mf * 4 + i];
    }
    __syncthreads();
    if (tid < MBLK) {
        float sc = bv[0];
#pragma unroll
        for (int w = 0; w < 8; ++w) sc += ssum[w][tid];
        score[b * SS + s0 + tid] = sc;
    }
}

// ---------------- K3a: softmax over S per batch ----------------
__global__ void softmax_kernel(const float* __restrict__ score, float* __restrict__ weights) {
    __shared__ float red[8];
    const int b = blockIdx.x;
    const int t = threadIdx.x;  // 256
    float local[8];
    float mx = -1e30f;
#pragma unroll
    for (int i = 0; i < 8; ++i) {
        local[i] = score[b * SS + i * 256 + t];
        mx = fmaxf(mx, local[i]);
    }
    for (int off = 1; off < 64; off <<= 1) mx = fmaxf(mx, __shfl_xor(mx, off));
    if ((t & 63) == 0) red[t >> 6] = mx;
    __syncthreads();
    const float m = fmaxf(fmaxf(red[0], red[1]), fmaxf(red[2], red[3]));
    float sum = 0.f;
#pragma unroll
    for (int i = 0; i < 8; ++i) {
        local[i] = __expf(local[i] - m);
        sum += local[i];
    }
    for (int off = 1; off < 64; off <<= 1) sum += __shfl_xor(sum, off);
    if ((t & 63) == 0) red[4 + (t >> 6)] = sum;
    __syncthreads();
    const float inv = 1.f / (red[4] + red[5] + red[6] + red[7]);
#pragma unroll
    for (int i = 0; i < 8; ++i) weights[b * SS + i * 256 + t] = local[i] * inv;
}

// ---------------- K3b: context[b,d] = sum_s w[b,s] * values[b,s,d] ----------------
__global__ void context_kernel(const float* __restrict__ values, const float* __restrict__ weights,
                               float* __restrict__ ctx) {
    __shared__ float ws[SS];          // 8 KB
    __shared__ f32x4 red[16][16];     // 4 KB
    const int b = blockIdx.x;   // 32
    const int dc = blockIdx.y;  // 16
    const int t = threadIdx.x;  // 256
    for (int i = t; i < SS; i += 256) ws[i] = weights[b * SS + i];
    __syncthreads();
    const int dt = t & 15;      // 16 d-threads (64 cols)
    const int ph = t >> 4;      // 16 s-phases
    const int d = dc * 64 + dt * 4;
    const float* vb = values + (size_t)b * SS * DD + d;
    f32x4 acc = {0.f, 0.f, 0.f, 0.f};
#pragma unroll 8
    for (int s = ph; s < SS; s += 16) {
        const float w = ws[s];
        f32x4 v = ntload4(vb + (size_t)s * DD);
        acc[0] = fmaf(w, v[0], acc[0]);
        acc[1] = fmaf(w, v[1], acc[1]);
        acc[2] = fmaf(w, v[2], acc[2]);
        acc[3] = fmaf(w, v[3], acc[3]);
    }
    red[ph][dt] = acc;
    __syncthreads();
    if (t < 16) {
        f32x4 r = red[0][t];
#pragma unroll
        for (int w = 1; w < 16; ++w) {
            f32x4 x = red[w][t];
#pragma unroll
            for (int i = 0; i < 4; ++i) r[i] += x[i];
        }
        *reinterpret_cast<f32x4*>(ctx + (size_t)b * DD + dc * 64 + t * 4) = r;
    }
}

extern "C" void kernel_launch(void* const* d_in, const int* in_sizes, int n_in,
                              void* d_out, int out_size, void* d_ws, size_t ws_size,
                              hipStream_t stream) {
    const float* query  = (const float*)d_in[0];
    const float* values = (const float*)d_in[1];
    const float* w1     = (const float*)d_in[2];
    const float* b1     = (const float*)d_in[3];
    const float* w2     = (const float*)d_in[4];
    const float* b2     = (const float*)d_in[5];
    const float* wv     = (const float*)d_in[6];
    const float* bv     = (const float*)d_in[7];

    float* ctx     = (float*)d_out;                    // [B, D]
    float* weights = (float*)d_out + (size_t)BB * DD;  // [B, S, 1]

    float* qp2           = (float*)d_ws;                                  // 128 KB
    unsigned short* w2q  = (unsigned short*)((char*)d_ws + 131072);       // 2 MB
    float* score         = (float*)((char*)d_ws + 131072 + 2097152);      // 256 KB

    zero_kernel<<<dim3(BB * UU / 256), 256, 0, stream>>>(qp2);
    qproj_kernel<<<dim3(4, 8, 8), 256, 0, stream>>>(query, w1, b1, b2, qp2);
    w2q_kernel<<<dim3(256), 256, 0, stream>>>(w2, w2q);
    score_kernel<<<dim3(BB * SS / MBLK), 512, 0, stream>>>(values, w2q, qp2, wv, bv, score);
    softmax_kernel<<<dim3(BB), 256, 0, stream>>>(score, weights);
    context_kernel<<<dim3(BB, 16), 256, 0, stream>>>(values, weights, ctx);
}